// Round 4
// baseline (278.338 us; speedup 1.0000x reference)
//
#include <hip/hip_runtime.h>
#include <math.h>

// Problem constants (from reference)
#define BATCH 4
#define N_ANCHORS 211200
#define CHANNELS 256
#define FM_H 200
#define FM_W 176
#define NKP 4096
#define PLANE (FM_H * FM_W)                   // 35200 floats

#define BOXES_ELEMS (BATCH * N_ANCHORS * 7)   // 5,913,600

// BEV: 10 y-strips of 20 rows per plane; stage 21 rows (overlap row for the
// y+1 tap), double-buffered: 2 x 1024 float4 = 32768 B LDS -> 4 blocks/CU,
// with zero-LDS decode blocks co-residing on top.
#define QSTRIPS 10
#define ROWS_PER_STRIP 20
#define STRIP_V4 924                          // 21 rows * 44 float4
#define STRIP_V4_LAST 880                     // q=9: 20 rows only
#define BUCKET_CAP 2048                       // max records per (b,q) bucket
#define BEV_BLOCKS (BATCH * CHANNELS)         // 1024 (one per plane)

// Decode: barrier-free register streaming, 4 boxes/thread, 1024 boxes/block.
#define DEC_BLOCKS (BATCH * N_ANCHORS / 1024) // 825 exactly
#define TOTAL_BLOCKS (BEV_BLOCKS + DEC_BLOCKS)

#define NBUCKET (BATCH * QSTRIPS)             // 40

// Async global->LDS, 16B/lane (wave-uniform LDS base + lane*16; staging index
// is lane-linear per wave so the linear layout matches).
#define GLL(g, l) __builtin_amdgcn_global_load_lds(                        \
    (const __attribute__((address_space(1))) void*)(g),                    \
    (__attribute__((address_space(3))) void*)(l), 16, 0, 0)

// ---------------------------------------------------------------------------
// Kernel 1: keypoint transform + stable k-sorted bucketing into 10 strips,
// one block per batch b (4 blocks x 1024 threads, thread t -> k = 4t..4t+3).
// Record (16 B): meta = a0 | dx<<12 | dy<<13 | k<<14, wx, WY0, WY1 where
//   a0 = strip-local tap addr (rowoff*176 + x0, rowoff in [0,19], 12 bits)
//   dx = x1-valid (adds 1 col), dy = y1-valid (adds 176)
//   WY0 = (1-wy)*fy0, WY1 = wy*dy  (row-valid flags folded into weights).
// Masked taps re-read the UNMASKED address (dyo/dx = 0), so garbage LDS is
// never read even with weight 0 (no 0*NaN hazard).
// Stable counting sort by q: per-thread counts packed into three u64s
// (13-bit fields, q0-3|q4-7|q8-9), shfl inclusive scan + cross-wave combine.
// Writes counts[] directly; no global atomics; no memset launch.
// ---------------------------------------------------------------------------
__global__ __launch_bounds__(1024) void kp_transform_sort_kernel(
    const float* __restrict__ kp,        // [B, K, 3]
    int* __restrict__ counts,            // [40]
    float4* __restrict__ bucket)         // [40 * BUCKET_CAP] records
{
    __shared__ unsigned long long w0[16], w1[16], w2[16];

    const int b    = blockIdx.x;
    const int tid  = threadIdx.x;
    const int lane = tid & 63;
    const int wid  = tid >> 6;

    // Load 4 keypoints (12 consecutive floats = 3 float4).
    const float4* kp4 = (const float4*)(kp + (size_t)b * NKP * 3) + tid * 3;
    float4 p0 = kp4[0], p1 = kp4[1], p2 = kp4[2];
    float kxJ[4] = {p0.x, p0.w, p1.z, p2.y};
    float kyJ[4] = {p0.y, p1.x, p1.w, p2.z};

    unsigned metaJ[4];
    float wxJ[4], wy0J[4], wy1J[4];
    int qJ[4];
    unsigned long long P0 = 0, P1 = 0, P2 = 0;

#pragma unroll
    for (int j = 0; j < 4; ++j) {
        const int k = tid * 4 + j;
        // Verbatim transform math (keeps absmax behavior).
        float ix_idx = kxJ[j] / 0.4f;
        float iy_idx = (kyJ[j] + 40.0f) / 0.4f;
        ix_idx = fminf(fmaxf(ix_idx, 0.0f), (float)(FM_W - 1));
        iy_idx = fminf(fmaxf(iy_idx, 0.0f), (float)(FM_H - 1));
        float nx = 2.0f * (ix_idx / (float)(FM_W - 2)) - 1.0f;
        float ny = 2.0f * (iy_idx / (float)(FM_H - 2)) - 1.0f;
        // grid flip: width coord gets ny, height coord gets nx
        float ix = (ny + 1.0f) * 0.5f * (float)(FM_W - 1);
        float iy = (nx + 1.0f) * 0.5f * (float)(FM_H - 1);

        float x0f = floorf(ix);
        float y0f = floorf(iy);
        float wx = ix - x0f;
        float wy = iy - y0f;
        int x0 = (int)x0f;      // in [0, 175]
        int y0 = (int)y0f;      // in [0, 199] for this geometry

        int q = min(y0 / ROWS_PER_STRIP, QSTRIPS - 1);
        int yc0 = min(y0, FM_H - 1);
        int rowoff = yc0 - q * ROWS_PER_STRIP;          // [0, 19]
        int dx = (x0 + 1 <= FM_W - 1) ? 1 : 0;
        int dy = (y0 + 1 <= FM_H - 1) ? 1 : 0;
        float fy0 = (y0 <= FM_H - 1) ? 1.0f : 0.0f;

        unsigned a0 = (unsigned)(rowoff * FM_W + x0);   // 12 bits
        metaJ[j] = a0 | ((unsigned)dx << 12) | ((unsigned)dy << 13)
                 | ((unsigned)k << 14);
        wxJ[j]  = wx;
        wy0J[j] = (1.0f - wy) * fy0;
        wy1J[j] = wy * (float)dy;
        qJ[j]   = q;

        if      (q < 4) P0 += 1ull << (13 * q);
        else if (q < 8) P1 += 1ull << (13 * (q - 4));
        else            P2 += 1ull << (13 * (q - 8));
    }

    // Inclusive scan over 1024 threads: in-wave shfl + cross-wave combine.
    unsigned long long v0 = P0, v1 = P1, v2 = P2;
#pragma unroll
    for (int off = 1; off < 64; off <<= 1) {
        unsigned long long t0 = __shfl_up(v0, off);
        unsigned long long t1 = __shfl_up(v1, off);
        unsigned long long t2 = __shfl_up(v2, off);
        if (lane >= off) { v0 += t0; v1 += t1; v2 += t2; }
    }
    if (lane == 63) { w0[wid] = v0; w1[wid] = v1; w2[wid] = v2; }
    __syncthreads();
    if (wid == 0 && lane < 16) {
        unsigned long long a0s = w0[lane], a1s = w1[lane], a2s = w2[lane];
#pragma unroll
        for (int off = 1; off < 16; off <<= 1) {
            unsigned long long t0 = __shfl_up(a0s, off);
            unsigned long long t1 = __shfl_up(a1s, off);
            unsigned long long t2 = __shfl_up(a2s, off);
            if (lane >= off) { a0s += t0; a1s += t1; a2s += t2; }
        }
        w0[lane] = a0s; w1[lane] = a1s; w2[lane] = a2s;
    }
    __syncthreads();

    unsigned long long b0 = wid ? w0[wid - 1] : 0ull;
    unsigned long long b1 = wid ? w1[wid - 1] : 0ull;
    unsigned long long b2 = wid ? w2[wid - 1] : 0ull;
    unsigned long long e0 = v0 + b0 - P0;   // exclusive prefix
    unsigned long long e1 = v1 + b1 - P1;
    unsigned long long e2 = v2 + b2 - P2;
    unsigned long long t0 = w0[15], t1 = w1[15], t2 = w2[15];

    if (tid < QSTRIPS) {
        unsigned long long t = (tid < 4) ? t0 : (tid < 8) ? t1 : t2;
        int sh = (tid < 4) ? 13 * tid : (tid < 8) ? 13 * (tid - 4) : 13 * (tid - 8);
        counts[b * QSTRIPS + tid] = (int)((t >> sh) & 0x1FFFull);
    }

    int slot[QSTRIPS];
#pragma unroll
    for (int q = 0; q < QSTRIPS; ++q) {
        unsigned long long e = (q < 4) ? e0 : (q < 8) ? e1 : e2;
        int sh = (q < 4) ? 13 * q : (q < 8) ? 13 * (q - 4) : 13 * (q - 8);
        slot[q] = (int)((e >> sh) & 0x1FFFull);
    }

#pragma unroll
    for (int j = 0; j < 4; ++j) {
        int q = qJ[j];
        float4 r;
        r.x = __uint_as_float(metaJ[j]);
        r.y = wxJ[j];
        r.z = wy0J[j];
        r.w = wy1J[j];
        int s = slot[q];
        if (s < BUCKET_CAP)    // capacity guard (never hit for uniform kp)
            bucket[(size_t)(b * QSTRIPS + q) * BUCKET_CAP + s] = r;
        slot[q] = s + 1;
    }
}

// ---------------------------------------------------------------------------
// Kernel 2: fused bev-gather + decode.
// bev block (bid < 1024): one plane, 10 strips double-buffered with COUNTED
// vmcnt(4) + raw s_barrier (T3/T4): stage s+1's loads stay in flight across
// the barriers while strip s is scanned -> continuous HBM stream, no per-strip
// full drain. Uniform 4 GLL/wave per stage (tail source-clamped) makes the
// count exact.
// decode block (bid >= 1024): barrier-free register streaming, no LDS ->
// co-resides with bev blocks and soaks BW whenever bev waves wait.
// ---------------------------------------------------------------------------
__global__ __launch_bounds__(256, 4) void fused_kernel(
    const float* __restrict__ deltas,
    const float* __restrict__ anchors,
    const float* __restrict__ fm,          // [B, C, H, W]
    const int* __restrict__ counts,        // [40]
    const float4* __restrict__ bucket,     // [40 * BUCKET_CAP]
    float* __restrict__ out_boxes,
    float* __restrict__ out_bev)           // [B, C, K]
{
    __shared__ float strip[2][4096];       // 2 x 16384 B (924 used + pad)

    const int tid = threadIdx.x;
    const int bid = blockIdx.x;

    if (bid < BEV_BLOCKS) {
        // ---- BEV plane block, 10 dbuf strips ----
        const int plane = bid;
        const int b = plane >> 8;          // / CHANNELS
        const float* gsrc = fm + (size_t)plane * PLANE;
        float* outp = out_bev + (size_t)plane * NKP;

        // Stage strip s (21 rows; q=9 only 20) -> strip[s&1], 4 GLL/thread,
        // tail lanes clamp the SOURCE (dup loads) so every wave issues
        // exactly 4 VMEM ops -> vmcnt arithmetic is uniform.
#define STAGE(s)                                                            \
        {                                                                   \
            const int climit = ((s) == QSTRIPS - 1) ? (STRIP_V4_LAST - 1)   \
                                                    : (STRIP_V4 - 1);       \
            const float* src = gsrc + (s) * (ROWS_PER_STRIP * FM_W);        \
            float* dst = &strip[(s) & 1][0];                                \
            _Pragma("unroll")                                               \
            for (int it = 0; it < 4; ++it) {                                \
                int idx = tid + it * 256;                                   \
                int ci = idx > climit ? climit : idx;                       \
                GLL(src + ci * 4, dst + idx * 4);                           \
            }                                                               \
        }

        STAGE(0);

#pragma unroll 1
        for (int s = 0; s < QSTRIPS; ++s) {
            if (s + 1 < QSTRIPS) {
                STAGE(s + 1);
                __builtin_amdgcn_sched_barrier(0);
                asm volatile("s_waitcnt vmcnt(4)" ::: "memory");  // strip s landed
            } else {
                __builtin_amdgcn_sched_barrier(0);
                asm volatile("s_waitcnt vmcnt(0)" ::: "memory");
            }
            __builtin_amdgcn_s_barrier();
            __builtin_amdgcn_sched_barrier(0);

            const int bq = b * QSTRIPS + s;
            const int cnt = counts[bq];
            const float4* bk = bucket + (size_t)bq * BUCKET_CAP;
            const float* buf = strip[s & 1];

            for (int i = tid; i < cnt; i += 256) {
                float4 rr = bk[i];
                unsigned meta = __float_as_uint(rr.x);
                int a0  = meta & 0xFFF;
                int dx  = (meta >> 12) & 1;
                int dyo = ((meta >> 13) & 1) * FM_W;
                int k   = meta >> 14;
                float wx = rr.y, WY0 = rr.z, WY1 = rr.w;
                float v00 = buf[a0];
                float v01 = buf[a0 + dx];
                float v10 = buf[a0 + dyo];
                float v11 = buf[a0 + dyo + dx];
                float ex  = 1.0f - wx;
                float wxm = wx * (float)dx;
                outp[k] = (v00 * ex + v01 * wxm) * WY0
                        + (v10 * ex + v11 * wxm) * WY1;
            }

            __builtin_amdgcn_sched_barrier(0);
            __builtin_amdgcn_s_barrier();   // protect strip[s&1] before restage
            __builtin_amdgcn_sched_barrier(0);
        }
#undef STAGE
    } else {
        // ---- decode: 4 boxes/thread in registers, no LDS, no barriers ----
        const size_t T = (size_t)(bid - BEV_BLOCKS) * 256 + tid;  // < 211200
        const float4* gd = (const float4*)deltas  + T * 7;
        const float4* ga = (const float4*)anchors + T * 7;

        float D[28], A[28];
#pragma unroll
        for (int i = 0; i < 7; ++i) {
            *(float4*)&D[i * 4] = gd[i];
            *(float4*)&A[i * 4] = ga[i];
        }

#pragma unroll
        for (int m = 0; m < 4; ++m) {
            const int o = m * 7;
            float aw = A[o + 3], al = A[o + 4], ah = A[o + 5];
            float dn = sqrtf(aw * aw + al * al);
            float r0 = D[o + 0] * dn + A[o + 0];
            float r1 = D[o + 1] * dn + A[o + 1];
            float r2 = D[o + 2] * ah + A[o + 2];
            float r3 = expf(D[o + 3]) * aw;
            float r4 = expf(D[o + 4]) * al;
            float r5 = expf(D[o + 5]) * ah;
            float r6 = D[o + 6] + A[o + 6];
            D[o + 0] = r0; D[o + 1] = r1; D[o + 2] = r2; D[o + 3] = r3;
            D[o + 4] = r4; D[o + 5] = r5; D[o + 6] = r6;
        }

        float4* go = (float4*)out_boxes + T * 7;
#pragma unroll
        for (int i = 0; i < 7; ++i) go[i] = *(const float4*)&D[i * 4];
    }
}

extern "C" void kernel_launch(void* const* d_in, const int* in_sizes, int n_in,
                              void* d_out, int out_size, void* d_ws, size_t ws_size,
                              hipStream_t stream)
{
    const float* deltas  = (const float*)d_in[0];
    const float* anchors = (const float*)d_in[1];
    const float* fm      = (const float*)d_in[2];
    const float* kp      = (const float*)d_in[3];

    float* out_boxes = (float*)d_out;
    float* out_bev   = (float*)d_out + BOXES_ELEMS;

    // Workspace: [0,160) counts, [256, 256+1.31MB) bucket records.
    int*    counts = (int*)d_ws;
    float4* bucket = (float4*)((char*)d_ws + 256);

    kp_transform_sort_kernel<<<BATCH, 1024, 0, stream>>>(kp, counts, bucket);

    fused_kernel<<<TOTAL_BLOCKS, 256, 0, stream>>>(
        deltas, anchors, fm, counts, bucket, out_boxes, out_bev);
}